// Round 21
// baseline (196.998 us; speedup 1.0000x reference)
//
#include <hip/hip_runtime.h>
#include <hip/hip_fp16.h>
#include <math.h>

#define NN   50000
#define EE   1600000
#define FD   128
#define OUTD 40
#define NEG  0.2f
#define NB   196           // ceil(NN/256) buckets of 256 nodes
#define ABLK 256           // bplace blocks / edge slices
#define ACH  (EE/ABLK)     // 6250 edges per block (exact)
#define SLOTB 80           // per-(block,bucket) slot capacity (+8.5 sigma)
#define BMAX 9216          // per-bucket csr region (+11 sigma over 8163 mean)
#define BPSZ (9*4*64*8)    // packed B elems
#define SETUP_BLOCKS 2304  // 256 bplace + roles + convx
#define POST_SMEM (4*FD*4) // per-wave H staging only (2 KB); Wp/bp via L1

__device__ __forceinline__ float lrelu(float v) { return v > 0.f ? v : NEG * v; }

__device__ __forceinline__ int fenc(float f) { int b = __float_as_int(f); return b < 0 ? (b ^ 0x7FFFFFFF) : b; }
__device__ __forceinline__ float fdec(int v) { v = v < 0 ? (v ^ 0x7FFFFFFF) : v; return __int_as_float(v); }

__device__ __forceinline__ unsigned short f2bf(float f) {
  unsigned int u = __float_as_uint(f);
  unsigned int r = u + 0x7FFFu + ((u >> 16) & 1u);
  return (unsigned short)(r >> 16);
}

typedef short bf16x8 __attribute__((ext_vector_type(8)));
typedef float f32x4  __attribute__((ext_vector_type(4)));

// ================= k_setup: bplace + precompute + pack + convert =================
// blocks 0-255: CSR bplace ; 256-263: Wp ; 264: scalars ; 272-415: pack ; 416+: convx
__global__ __launch_bounds__(256) void k_setup(
    const float* __restrict__ X,
    const int* __restrict__ srcE, const int* __restrict__ dstE,
    const float* __restrict__ Wl0, const float* __restrict__ Wr0, const float* __restrict__ ar0,
    const float* __restrict__ br0,
    const float* __restrict__ Wl1, const float* __restrict__ Wr1, const float* __restrict__ ar1,
    const float* __restrict__ br1,
    const float* __restrict__ Wm1, const float* __restrict__ bm1,
    const float* __restrict__ Wm2, const float* __restrict__ bm2,
    unsigned short* __restrict__ XB,
    unsigned short* __restrict__ Bp0, unsigned short* __restrict__ Bp1,
    float* __restrict__ brd0, float* __restrict__ brd1,
    float* __restrict__ Wp, float* __restrict__ bp,
    int* __restrict__ mAL,
    int* __restrict__ cnt, unsigned int* __restrict__ pslot)
{
  __shared__ int lcur[NB];
  int t = threadIdx.x;
  int bid = blockIdx.x;
  if (bid < 256) {
    if (t < NB) lcur[t] = 0;
    __syncthreads();
    int e0 = bid * ACH;
    size_t base = (size_t)bid * NB * SLOTB;
    for (int e = e0 + t; e < e0 + ACH; e += 256) {
      int d = dstE[e];
      int b = d >> 8;
      int p = atomicAdd(&lcur[b], 1);
      pslot[base + (size_t)b*SLOTB + p] = (unsigned int)srcE[e] | ((unsigned int)(d & 255) << 16);
    }
    __syncthreads();
    if (t < NB) cnt[bid*NB + t] = lcur[t];
  } else if (bid < 264) {
    int rb = bid - 256;
    for (int i = rb*256 + t; i < FD*OUTD; i += 8*256) {
      int k = i / OUTD, o = i % OUTD;
      float s = 0.f;
      for (int j = 0; j < 64; ++j) s += Wm1[k*64 + j] * Wm2[j*OUTD + o];
      Wp[i] = s;
    }
  } else if (bid == 264) {
    if (t < OUTD) {
      float s = bm2[t];
      for (int j = 0; j < 64; ++j) s += bm1[j] * Wm2[j*OUTD + t];
      bp[t] = s;
    }
    if (t >= 64 && t < 68) {
      int idx = t - 64, l = idx >> 1, h = idx & 1;
      const float* br = l ? br1 : br0;
      const float* ar = l ? ar1 : ar0;
      float s = 0.f;
      for (int c = 0; c < 64; ++c) s += br[h*64 + c] * ar[h*64 + c];
      (l ? brd1 : brd0)[h] = s;
    }
    if (t >= 96 && t < 100) mAL[t - 96] = 0x80000000;
  } else if (bid >= 272 && bid < 416) {
    bool l1 = (bid >= 344);
    const float* Wl = l1 ? Wl1 : Wl0;
    const float* Wr = l1 ? Wr1 : Wr0;
    const float* ar = l1 ? ar1 : ar0;
    unsigned short* Bp = l1 ? Bp1 : Bp0;
    int i = (bid - (l1 ? 344 : 272))*256 + t;
    if (i < BPSZ) {
      int j = i & 7, lane = (i >> 3) & 63, ks = (i >> 9) & 3, ct = i >> 11;
      int k = ks*32 + 8*(lane >> 4) + j;
      int c = lane & 15;
      float v = 0.f;
      if (ct < 8) v = Wl[k*FD + ct*16 + c];
      else if (c < 2) {
        for (int c2 = 0; c2 < 64; ++c2) v += Wr[k*FD + c*64 + c2] * ar[c*64 + c2];
      }
      Bp[i] = f2bf(v);
    }
  } else if (bid >= 416) {
    const int n4 = NN*FD/4;
    for (int i = (bid-416)*256 + t; i < n4; i += (gridDim.x-416)*256) {
      float4 v = ((const float4*)X)[i];
      ushort4 o;
      o.x = f2bf(v.x); o.y = f2bf(v.y); o.z = f2bf(v.z); o.w = f2bf(v.w);
      ((ushort4*)XB)[i] = o;
    }
  }
}

// ================= k_bfgemm: bfinal (blocks 0-195) + layer-0 MFMA gemm (196+) =================
#define SMEM_BYTES 59392
__global__ __launch_bounds__(256) void k_bfgemm(
    const unsigned int* __restrict__ pslot, const int* __restrict__ cnt,
    int* __restrict__ row_off, unsigned short* __restrict__ csr16,
    const unsigned short* __restrict__ XB, const unsigned short* __restrict__ Bp,
    const float* __restrict__ bl, const float* __restrict__ al, const float* __restrict__ brd,
    __half* __restrict__ XLh, float* __restrict__ AL, float* __restrict__ AR,
    int* __restrict__ mAL)
{
  __shared__ char smem[SMEM_BYTES];
  int t = threadIdx.x;
  int bid = blockIdx.x;
  if (bid < NB) {
    int* scnt = (int*)smem;
    int* soff = (int*)(smem + 1024);
    unsigned int* pairs = (unsigned int*)(smem + 2048);
    unsigned short* stage = (unsigned short*)(smem + 38912);
    int* hist = (int*)(smem + 57344);
    int* rel  = (int*)(smem + 58368);
    int g = bid;
    int v = cnt[t*NB + g];
    scnt[t] = v;
    soff[t] = v;
    __syncthreads();
    #pragma unroll
    for (int off = 1; off < 256; off <<= 1) {
      int u = (t >= off) ? soff[t - off] : 0;
      __syncthreads();
      soff[t] += u;
      __syncthreads();
    }
    int cnt_g = soff[255];
    int mybase = soff[t] - v;
    {
      const unsigned int* sp = pslot + (size_t)t * NB * SLOTB + (size_t)g * SLOTB;
      for (int i = 0; i < v; ++i) pairs[mybase + i] = sp[i];
    }
    __syncthreads();
    hist[t] = 0;
    __syncthreads();
    for (int i = t; i < cnt_g; i += 256)
      atomicAdd(&hist[pairs[i] >> 16], 1);
    __syncthreads();
    int hv = hist[t];
    rel[t] = hv;
    __syncthreads();
    #pragma unroll
    for (int off = 1; off < 256; off <<= 1) {
      int u = (t >= off) ? rel[t - off] : 0;
      __syncthreads();
      rel[t] += u;
      __syncthreads();
    }
    int excl = rel[t] - hv;
    __syncthreads();
    rel[t] = excl;
    row_off[g*257 + t] = g*BMAX + excl;
    if (t == 0) row_off[g*257 + 256] = g*BMAX + cnt_g;
    hist[t] = 0;
    __syncthreads();
    for (int i = t; i < cnt_g; i += 256) {
      unsigned int p = pairs[i];
      int j = p >> 16;
      int l = atomicAdd(&hist[j], 1);
      stage[rel[j] + l] = (unsigned short)(p & 0xFFFF);
    }
    __syncthreads();
    size_t cbase = (size_t)g * BMAX;
    for (int i = t; i < cnt_g; i += 256) csr16[cbase + i] = stage[i];
  } else {
    unsigned short* sB = (unsigned short*)smem;
    int* smaxI = (int*)(smem + 36864);
    if (t < 2) smaxI[t] = 0x80000000;
    {
      const uint4* s = (const uint4*)Bp;
      uint4* d = (uint4*)sB;
      #pragma unroll
      for (int i = 0; i < 9; ++i) d[t + i*256] = s[t + i*256];
    }
    __syncthreads();
    int w = t >> 6, l = t & 63;
    int c = l & 15, kg = l >> 4;
    int rowbase = (bid - NB)*64 + w*16;
    int arow = rowbase + c; if (arow > NN-1) arow = NN-1;
    f32x4 acc[9] = {};
    const bf16x8* sBf = (const bf16x8*)sB;
    #pragma unroll
    for (int ks = 0; ks < 4; ++ks) {
      bf16x8 afrag = *(const bf16x8*)(XB + (size_t)arow*FD + ks*32 + kg*8);
      #pragma unroll
      for (int ct = 0; ct < 9; ++ct)
        acc[ct] = __builtin_amdgcn_mfma_f32_16x16x32_bf16(afrag, sBf[(ct*4+ks)*64 + l], acc[ct], 0, 0, 0);
    }
    float pAL0[4] = {}, pAL1[4] = {};
    #pragma unroll
    for (int ct = 0; ct < 8; ++ct) {
      float bias = bl[ct*16 + c];
      float alv  = al[ct*16 + c];
      #pragma unroll
      for (int r = 0; r < 4; ++r) {
        int row = rowbase + kg*4 + r;
        float xv = acc[ct][r] + bias;
        if (row < NN) XLh[(size_t)row*FD + ct*16 + c] = __float2half(xv);
        if (ct < 4) pAL0[r] = fmaf(xv, alv, pAL0[r]);
        else        pAL1[r] = fmaf(xv, alv, pAL1[r]);
      }
    }
    if (c < 2) {
      float b = brd[c];
      #pragma unroll
      for (int r = 0; r < 4; ++r) {
        int row = rowbase + kg*4 + r;
        if (row < NN) AR[(size_t)row*2 + c] = acc[8][r] + b;
      }
    }
    float m0 = -INFINITY, m1 = -INFINITY;
    #pragma unroll
    for (int r = 0; r < 4; ++r) {
      float v0 = pAL0[r], v1 = pAL1[r];
      #pragma unroll
      for (int off = 1; off < 16; off <<= 1) { v0 += __shfl_xor(v0, off); v1 += __shfl_xor(v1, off); }
      int row = rowbase + kg*4 + r;
      if (c == 0 && row < NN) {
        AL[(size_t)row*2 + 0] = v0;
        AL[(size_t)row*2 + 1] = v1;
        m0 = fmaxf(m0, v0); m1 = fmaxf(m1, v1);
      }
    }
    if (c == 0) { atomicMax(&smaxI[0], fenc(m0)); atomicMax(&smaxI[1], fenc(m1)); }
    __syncthreads();
    if (t < 2) atomicMax(&mAL[t], smaxI[t]);
  }
}

// ---------------- MFMA GEMM (standalone, layer 1) ----------------
__global__ __launch_bounds__(256) void k_gemm_mfma(
    const unsigned short* __restrict__ XB, const unsigned short* __restrict__ Bp,
    const float* __restrict__ bl, const float* __restrict__ al, const float* __restrict__ brd,
    __half* __restrict__ XLh, float* __restrict__ AL, float* __restrict__ AR,
    int* __restrict__ mAL)
{
  __shared__ unsigned short sB[BPSZ];
  __shared__ int smaxI[2];
  int t = threadIdx.x;
  if (t < 2) smaxI[t] = 0x80000000;
  {
    const uint4* s = (const uint4*)Bp;
    uint4* d = (uint4*)sB;
    #pragma unroll
    for (int i = 0; i < 9; ++i) d[t + i*256] = s[t + i*256];
  }
  __syncthreads();
  int w = t >> 6, l = t & 63;
  int c = l & 15, kg = l >> 4;
  int rowbase = blockIdx.x*64 + w*16;
  int arow = rowbase + c; if (arow > NN-1) arow = NN-1;
  f32x4 acc[9] = {};
  const bf16x8* sBf = (const bf16x8*)sB;
  #pragma unroll
  for (int ks = 0; ks < 4; ++ks) {
    bf16x8 afrag = *(const bf16x8*)(XB + (size_t)arow*FD + ks*32 + kg*8);
    #pragma unroll
    for (int ct = 0; ct < 9; ++ct)
      acc[ct] = __builtin_amdgcn_mfma_f32_16x16x32_bf16(afrag, sBf[(ct*4+ks)*64 + l], acc[ct], 0, 0, 0);
  }
  float pAL0[4] = {}, pAL1[4] = {};
  #pragma unroll
  for (int ct = 0; ct < 8; ++ct) {
    float bias = bl[ct*16 + c];
    float alv  = al[ct*16 + c];
    #pragma unroll
    for (int r = 0; r < 4; ++r) {
      int row = rowbase + kg*4 + r;
      float xv = acc[ct][r] + bias;
      if (row < NN) XLh[(size_t)row*FD + ct*16 + c] = __float2half(xv);
      if (ct < 4) pAL0[r] = fmaf(xv, alv, pAL0[r]);
      else        pAL1[r] = fmaf(xv, alv, pAL1[r]);
    }
  }
  if (c < 2) {
    float b = brd[c];
    #pragma unroll
    for (int r = 0; r < 4; ++r) {
      int row = rowbase + kg*4 + r;
      if (row < NN) AR[(size_t)row*2 + c] = acc[8][r] + b;
    }
  }
  float m0 = -INFINITY, m1 = -INFINITY;
  #pragma unroll
  for (int r = 0; r < 4; ++r) {
    float v0 = pAL0[r], v1 = pAL1[r];
    #pragma unroll
    for (int off = 1; off < 16; off <<= 1) { v0 += __shfl_xor(v0, off); v1 += __shfl_xor(v1, off); }
    int row = rowbase + kg*4 + r;
    if (c == 0 && row < NN) {
      AL[(size_t)row*2 + 0] = v0;
      AL[(size_t)row*2 + 1] = v1;
      m0 = fmaxf(m0, v0); m1 = fmaxf(m1, v1);
    }
  }
  if (c == 0) { atomicMax(&smaxI[0], fenc(m0)); atomicMax(&smaxI[1], fenc(m1)); }
  __syncthreads();
  if (t < 2) atomicMax(&mAL[t], smaxI[t]);
}

// ---------------- fused attention + aggregation (+ barrier-free post on layer 1) ----------------
// BF16OUT=true : layer-0, writes bf16 features.
// BF16OUT=false: layer-1 + post_mp + log_softmax -> d_out, NO __syncthreads:
//   sH is per-wave (within-wave LDS ordering is implicit); Wp/bp read through L1
//   (20KB, L1-resident, coalesced across the 40 col-lanes).
template<bool BF16OUT>
__global__ __launch_bounds__(256) void k_agg(
    const __half* __restrict__ XLh, const float* __restrict__ AL,
    const float* __restrict__ AR, const int* __restrict__ mAL,
    const int* __restrict__ row_off, const unsigned short* __restrict__ csr16,
    const float* __restrict__ Wp, const float* __restrict__ bp,
    float* __restrict__ out, unsigned short* __restrict__ OUTb)
{
  extern __shared__ char dynsmem[];
  float* sH = (float*)dynsmem;             // [4][FD] per-wave
  int t = threadIdx.x;
  int node = blockIdx.x * 4 + (t >> 6);    // NN % 4 == 0: all nodes valid
  int lane = t & 63;
  int g = lane >> 4, l = lane & 15;
  bool h1 = (l & 8) != 0;
  float2 ar = ((const float2*)AR)[node];
  float m0 = lrelu(fdec(mAL[0]) + ar.x);
  float m1 = lrelu(fdec(mAL[1]) + ar.y);
  float ar_s = h1 ? ar.y : ar.x;
  float m_s  = h1 ? m1 : m0;
  int ro = node + (node >> 8);
  int beg = row_off[ro], end = row_off[ro + 1];
  float facc[8] = {};
  __half2 hacc[4];
  #pragma unroll
  for (int q = 0; q < 4; ++q) hacc[q] = __half2half2(__float2half(0.f));
  float s_acc = 0.f;
  int flushcnt = 0;
  if (beg < end) {
    int em1 = end - 1;
    int s0 = csr16[min(beg + g,      em1)];
    int s1 = csr16[min(beg + 4 + g,  em1)];
    int s2 = csr16[min(beg + 8 + g,  em1)];
    int s3 = csr16[min(beg + 12 + g, em1)];
    for (int i = beg; i < end; i += 16) {
      int c0 = s0, c1 = s1, c2 = s2, c3 = s3;
      bool v0 = (i + g) < end, v1 = (i + 4 + g) < end,
           v2 = (i + 8 + g) < end, v3 = (i + 12 + g) < end;
      int ni = i + 16;
      if (ni < end) {
        s0 = csr16[min(ni + g,      em1)];
        s1 = csr16[min(ni + 4 + g,  em1)];
        s2 = csr16[min(ni + 8 + g,  em1)];
        s3 = csr16[min(ni + 12 + g, em1)];
      }
      uint4 d0 = *(const uint4*)(XLh + (size_t)c0*FD + 8*l);
      uint4 d1 = *(const uint4*)(XLh + (size_t)c1*FD + 8*l);
      uint4 d2 = *(const uint4*)(XLh + (size_t)c2*FD + 8*l);
      uint4 d3 = *(const uint4*)(XLh + (size_t)c3*FD + 8*l);
      float2 a0 = ((const float2*)AL)[c0];
      float2 a1 = ((const float2*)AL)[c1];
      float2 a2 = ((const float2*)AL)[c2];
      float2 a3 = ((const float2*)AL)[c3];
      float w0 = __expf(lrelu((h1 ? a0.y : a0.x) + ar_s) - m_s);
      float w1 = __expf(lrelu((h1 ? a1.y : a1.x) + ar_s) - m_s);
      float w2 = __expf(lrelu((h1 ? a2.y : a2.x) + ar_s) - m_s);
      float w3 = __expf(lrelu((h1 ? a3.y : a3.x) + ar_s) - m_s);
      w0 = v0 ? w0 : 0.f; w1 = v1 ? w1 : 0.f;
      w2 = v2 ? w2 : 0.f; w3 = v3 ? w3 : 0.f;
      s_acc += (w0 + w1) + (w2 + w3);
      __half2 h0 = __half2half2(__float2half(w0));
      __half2 h1w = __half2half2(__float2half(w1));
      __half2 h2 = __half2half2(__float2half(w2));
      __half2 h3 = __half2half2(__float2half(w3));
      const __half2* f0 = (const __half2*)&d0;
      const __half2* f1 = (const __half2*)&d1;
      const __half2* f2 = (const __half2*)&d2;
      const __half2* f3 = (const __half2*)&d3;
      #pragma unroll
      for (int q = 0; q < 4; ++q) {
        hacc[q] = __hfma2(h0,  f0[q], hacc[q]);
        hacc[q] = __hfma2(h1w, f1[q], hacc[q]);
        hacc[q] = __hfma2(h2,  f2[q], hacc[q]);
        hacc[q] = __hfma2(h3,  f3[q], hacc[q]);
      }
      if (++flushcnt == 8) {
        flushcnt = 0;
        #pragma unroll
        for (int q = 0; q < 4; ++q) {
          float2 f = __half22float2(hacc[q]);
          facc[2*q] += f.x; facc[2*q+1] += f.y;
          hacc[q] = __half2half2(__float2half(0.f));
        }
      }
    }
    #pragma unroll
    for (int q = 0; q < 4; ++q) {
      float2 f = __half22float2(hacc[q]);
      facc[2*q] += f.x; facc[2*q+1] += f.y;
    }
  }
  #pragma unroll
  for (int off = 16; off < 64; off <<= 1) {   // allreduce across g-groups
    s_acc += __shfl_xor(s_acc, off);
    #pragma unroll
    for (int q = 0; q < 8; ++q) facc[q] += __shfl_xor(facc[q], off);
  }
  float sinv = 1.f / (s_acc + 1e-16f);
  float o[8];
  #pragma unroll
  for (int q = 0; q < 8; ++q) o[q] = fmaxf(facc[q]*sinv, 0.f);   // relu'd H dims [8l..8l+8)
  if constexpr (BF16OUT) {
    if (g == 0) {
      unsigned short ob[8];
      #pragma unroll
      for (int q = 0; q < 8; ++q) ob[q] = f2bf(o[q]);
      *(uint4*)&OUTb[(size_t)node*FD + 8*l] = *(uint4*)ob;
    }
  } else {
    // ---- fused post_mp + log_softmax, barrier-free ----
    float* myH = sH + (t >> 6) * FD;       // per-wave buffer, within-wave ordering only
    if (g == 0) {
      #pragma unroll
      for (int q = 0; q < 8; ++q) myH[8*l + q] = o[q];
    }
    int col = lane;
    float acc2 = 0.f;
    if (col < OUTD) {
      acc2 = bp[col];
      #pragma unroll 8
      for (int k = 0; k < FD; ++k)
        acc2 = fmaf(myH[k], Wp[k*OUTD + col], acc2);   // myH: LDS broadcast; Wp: L1 hit
    }
    float z = (col < OUTD) ? acc2 : -INFINITY;
    float mx = z;
    #pragma unroll
    for (int off = 1; off < 64; off <<= 1) mx = fmaxf(mx, __shfl_xor(mx, off));
    float ex = (col < OUTD) ? __expf(z - mx) : 0.f;
    float se = ex;
    #pragma unroll
    for (int off = 1; off < 64; off <<= 1) se += __shfl_xor(se, off);
    float lg = mx + __logf(se);
    if (col < OUTD) out[(size_t)node*OUTD + col] = z - lg;
  }
}

// ---------------- launch ----------------
extern "C" void kernel_launch(void* const* d_in, const int* in_sizes, int n_in,
                              void* d_out, int out_size, void* d_ws, size_t ws_size,
                              hipStream_t stream)
{
  const float* x   = (const float*)d_in[0];
  const int*   ei  = (const int*)d_in[1];
  const float* Wl0 = (const float*)d_in[2];
  const float* bl0 = (const float*)d_in[3];
  const float* Wr0 = (const float*)d_in[4];
  const float* br0 = (const float*)d_in[5];
  const float* al0 = (const float*)d_in[6];
  const float* ar0 = (const float*)d_in[7];
  const float* Wl1 = (const float*)d_in[8];
  const float* bl1 = (const float*)d_in[9];
  const float* Wr1 = (const float*)d_in[10];
  const float* br1 = (const float*)d_in[11];
  const float* al1 = (const float*)d_in[12];
  const float* ar1 = (const float*)d_in[13];
  const float* Wm1 = (const float*)d_in[14];
  const float* bm1 = (const float*)d_in[15];
  const float* Wm2 = (const float*)d_in[16];
  const float* bm2 = (const float*)d_in[17];
  const int* srcA = ei;
  const int* dstA = ei + EE;

  char* w = (char*)d_ws;
  __half* XLh    = (__half*)w;          w += (size_t)NN*FD*2;   // 12.8 MB
  float* bufB    = (float*)w;           w += (size_t)NN*FD*4;   // 25.6 MB (pslot/cnt overlay only)
  unsigned short* XB = (unsigned short*)w; w += (size_t)NN*FD*2; // 12.8 MB
  float* AL      = (float*)w;  w += (size_t)NN*2*4;
  float* AR      = (float*)w;  w += (size_t)NN*2*4;
  float* brd0    = (float*)w;  w += 16;
  float* brd1    = (float*)w;  w += 16;
  float* Wp      = (float*)w;  w += FD*OUTD*4;
  float* bp      = (float*)w;  w += 64*4;
  int* mAL       = (int*)w;    w += 4*4;
  int* row_off   = (int*)w;    w += (size_t)(NB*257 + 1)*4 + 12;
  unsigned short* csr16 = (unsigned short*)w; w += (size_t)NB*BMAX*2; // 3.6 MB
  unsigned short* Bp0   = (unsigned short*)w; w += BPSZ*2;
  unsigned short* Bp1   = (unsigned short*)w; w += BPSZ*2;
  unsigned int* pslot = (unsigned int*)bufB;                       // 16.05 MB overlay
  int* cnt = (int*)((char*)bufB + (size_t)ABLK*NB*SLOTB*4);        // 200 KB overlay

  // 1) setup + CSR pass A (merged, role-split)
  k_setup<<<SETUP_BLOCKS, 256, 0, stream>>>(x, srcA, dstA,
                                            Wl0, Wr0, ar0, br0, Wl1, Wr1, ar1, br1,
                                            Wm1, bm1, Wm2, bm2, XB, Bp0, Bp1,
                                            brd0, brd1, Wp, bp, mAL, cnt, pslot);

  // 2) CSR finalize + layer-0 gemm (merged, role-split)
  k_bfgemm<<<NB + (NN+63)/64, 256, 0, stream>>>(pslot, cnt, row_off, csr16,
                                                XB, Bp0, bl0, al0, brd0, XLh, AL, AR, mAL + 0);
  // 3) layer-0 agg
  k_agg<true><<<(NN+3)/4, 256, 0, stream>>>(XLh, AL, AR, mAL + 0, row_off, csr16,
                                            nullptr, nullptr, nullptr, XB);
  // 4) layer-1 gemm
  k_gemm_mfma<<<(NN+63)/64, 256, 0, stream>>>(XB, Bp1, bl1, al1, brd1, XLh, AL, AR, mAL + 2);
  // 5) layer-1 agg + fused post_mp + log_softmax -> d_out (barrier-free)
  k_agg<false><<<(NN+3)/4, 256, POST_SMEM, stream>>>(XLh, AL, AR, mAL + 2, row_off, csr16,
                                                     Wp, bp, (float*)d_out, nullptr);
}

// Round 22
// 186.916 us; speedup vs baseline: 1.0539x; 1.0539x over previous
//
#include <hip/hip_runtime.h>
#include <hip/hip_fp16.h>
#include <math.h>

#define NN   50000
#define EE   1600000
#define FD   128
#define OUTD 40
#define NEG  0.2f
#define NB   196           // ceil(NN/256) buckets of 256 nodes
#define ABLK 256           // bplace blocks / edge slices
#define ACH  (EE/ABLK)     // 6250 edges per block (exact)
#define SLOTB 80           // per-(block,bucket) slot capacity (+8.5 sigma)
#define BMAX 9216          // per-bucket csr region (+11 sigma over 8163 mean)
#define BPSZ (9*4*64*8)    // packed B elems
#define SETUP_BLOCKS 2304  // 256 bplace + roles + convx

__device__ __forceinline__ float lrelu(float v) { return v > 0.f ? v : NEG * v; }

__device__ __forceinline__ int fenc(float f) { int b = __float_as_int(f); return b < 0 ? (b ^ 0x7FFFFFFF) : b; }
__device__ __forceinline__ float fdec(int v) { v = v < 0 ? (v ^ 0x7FFFFFFF) : v; return __int_as_float(v); }

__device__ __forceinline__ unsigned short f2bf(float f) {
  unsigned int u = __float_as_uint(f);
  unsigned int r = u + 0x7FFFu + ((u >> 16) & 1u);
  return (unsigned short)(r >> 16);
}
__device__ __forceinline__ float bf2f(unsigned short b) {
  return __uint_as_float((unsigned int)b << 16);
}

typedef short bf16x8 __attribute__((ext_vector_type(8)));
typedef float f32x4  __attribute__((ext_vector_type(4)));

// ================= k_setup: bplace + precompute + pack + convert =================
// blocks 0-255: CSR bplace ; 256-263: Wp ; 264: scalars ; 272-415: pack ; 416+: convx
__global__ __launch_bounds__(256) void k_setup(
    const float* __restrict__ X,
    const int* __restrict__ srcE, const int* __restrict__ dstE,
    const float* __restrict__ Wl0, const float* __restrict__ Wr0, const float* __restrict__ ar0,
    const float* __restrict__ br0,
    const float* __restrict__ Wl1, const float* __restrict__ Wr1, const float* __restrict__ ar1,
    const float* __restrict__ br1,
    const float* __restrict__ Wm1, const float* __restrict__ bm1,
    const float* __restrict__ Wm2, const float* __restrict__ bm2,
    unsigned short* __restrict__ XB,
    unsigned short* __restrict__ Bp0, unsigned short* __restrict__ Bp1,
    float* __restrict__ brd0, float* __restrict__ brd1,
    float* __restrict__ Wp, float* __restrict__ bp,
    int* __restrict__ mAL,
    int* __restrict__ cnt, unsigned int* __restrict__ pslot)
{
  __shared__ int lcur[NB];
  int t = threadIdx.x;
  int bid = blockIdx.x;
  if (bid < 256) {
    if (t < NB) lcur[t] = 0;
    __syncthreads();
    int e0 = bid * ACH;
    size_t base = (size_t)bid * NB * SLOTB;
    for (int e = e0 + t; e < e0 + ACH; e += 256) {
      int d = dstE[e];
      int b = d >> 8;
      int p = atomicAdd(&lcur[b], 1);
      pslot[base + (size_t)b*SLOTB + p] = (unsigned int)srcE[e] | ((unsigned int)(d & 255) << 16);
    }
    __syncthreads();
    if (t < NB) cnt[bid*NB + t] = lcur[t];
  } else if (bid < 264) {
    int rb = bid - 256;
    for (int i = rb*256 + t; i < FD*OUTD; i += 8*256) {
      int k = i / OUTD, o = i % OUTD;
      float s = 0.f;
      for (int j = 0; j < 64; ++j) s += Wm1[k*64 + j] * Wm2[j*OUTD + o];
      Wp[i] = s;
    }
  } else if (bid == 264) {
    if (t < OUTD) {
      float s = bm2[t];
      for (int j = 0; j < 64; ++j) s += bm1[j] * Wm2[j*OUTD + t];
      bp[t] = s;
    }
    if (t >= 64 && t < 68) {
      int idx = t - 64, l = idx >> 1, h = idx & 1;
      const float* br = l ? br1 : br0;
      const float* ar = l ? ar1 : ar0;
      float s = 0.f;
      for (int c = 0; c < 64; ++c) s += br[h*64 + c] * ar[h*64 + c];
      (l ? brd1 : brd0)[h] = s;
    }
    if (t >= 96 && t < 100) mAL[t - 96] = 0x80000000;
  } else if (bid >= 272 && bid < 416) {
    bool l1 = (bid >= 344);
    const float* Wl = l1 ? Wl1 : Wl0;
    const float* Wr = l1 ? Wr1 : Wr0;
    const float* ar = l1 ? ar1 : ar0;
    unsigned short* Bp = l1 ? Bp1 : Bp0;
    int i = (bid - (l1 ? 344 : 272))*256 + t;
    if (i < BPSZ) {
      int j = i & 7, lane = (i >> 3) & 63, ks = (i >> 9) & 3, ct = i >> 11;
      int k = ks*32 + 8*(lane >> 4) + j;
      int c = lane & 15;
      float v = 0.f;
      if (ct < 8) v = Wl[k*FD + ct*16 + c];
      else if (c < 2) {
        for (int c2 = 0; c2 < 64; ++c2) v += Wr[k*FD + c*64 + c2] * ar[c*64 + c2];
      }
      Bp[i] = f2bf(v);
    }
  } else if (bid >= 416) {
    const int n4 = NN*FD/4;
    for (int i = (bid-416)*256 + t; i < n4; i += (gridDim.x-416)*256) {
      float4 v = ((const float4*)X)[i];
      ushort4 o;
      o.x = f2bf(v.x); o.y = f2bf(v.y); o.z = f2bf(v.z); o.w = f2bf(v.w);
      ((ushort4*)XB)[i] = o;
    }
  }
}

// ================= k_bfgemm: bfinal (blocks 0-195) + layer-0 MFMA gemm (196+) =================
#define SMEM_BYTES 59392
__global__ __launch_bounds__(256) void k_bfgemm(
    const unsigned int* __restrict__ pslot, const int* __restrict__ cnt,
    int* __restrict__ row_off, unsigned short* __restrict__ csr16,
    const unsigned short* __restrict__ XB, const unsigned short* __restrict__ Bp,
    const float* __restrict__ bl, const float* __restrict__ al, const float* __restrict__ brd,
    __half* __restrict__ XLh, float* __restrict__ AL, float* __restrict__ AR,
    int* __restrict__ mAL)
{
  __shared__ char smem[SMEM_BYTES];
  int t = threadIdx.x;
  int bid = blockIdx.x;
  if (bid < NB) {
    int* scnt = (int*)smem;
    int* soff = (int*)(smem + 1024);
    unsigned int* pairs = (unsigned int*)(smem + 2048);
    unsigned short* stage = (unsigned short*)(smem + 38912);
    int* hist = (int*)(smem + 57344);
    int* rel  = (int*)(smem + 58368);
    int g = bid;
    int v = cnt[t*NB + g];
    scnt[t] = v;
    soff[t] = v;
    __syncthreads();
    #pragma unroll
    for (int off = 1; off < 256; off <<= 1) {
      int u = (t >= off) ? soff[t - off] : 0;
      __syncthreads();
      soff[t] += u;
      __syncthreads();
    }
    int cnt_g = soff[255];
    int mybase = soff[t] - v;
    {
      const unsigned int* sp = pslot + (size_t)t * NB * SLOTB + (size_t)g * SLOTB;
      for (int i = 0; i < v; ++i) pairs[mybase + i] = sp[i];
    }
    __syncthreads();
    hist[t] = 0;
    __syncthreads();
    for (int i = t; i < cnt_g; i += 256)
      atomicAdd(&hist[pairs[i] >> 16], 1);
    __syncthreads();
    int hv = hist[t];
    rel[t] = hv;
    __syncthreads();
    #pragma unroll
    for (int off = 1; off < 256; off <<= 1) {
      int u = (t >= off) ? rel[t - off] : 0;
      __syncthreads();
      rel[t] += u;
      __syncthreads();
    }
    int excl = rel[t] - hv;
    __syncthreads();
    rel[t] = excl;
    row_off[g*257 + t] = g*BMAX + excl;
    if (t == 0) row_off[g*257 + 256] = g*BMAX + cnt_g;
    hist[t] = 0;
    __syncthreads();
    for (int i = t; i < cnt_g; i += 256) {
      unsigned int p = pairs[i];
      int j = p >> 16;
      int l = atomicAdd(&hist[j], 1);
      stage[rel[j] + l] = (unsigned short)(p & 0xFFFF);
    }
    __syncthreads();
    size_t cbase = (size_t)g * BMAX;
    for (int i = t; i < cnt_g; i += 256) csr16[cbase + i] = stage[i];
  } else {
    unsigned short* sB = (unsigned short*)smem;
    int* smaxI = (int*)(smem + 36864);
    if (t < 2) smaxI[t] = 0x80000000;
    {
      const uint4* s = (const uint4*)Bp;
      uint4* d = (uint4*)sB;
      #pragma unroll
      for (int i = 0; i < 9; ++i) d[t + i*256] = s[t + i*256];
    }
    __syncthreads();
    int w = t >> 6, l = t & 63;
    int c = l & 15, kg = l >> 4;
    int rowbase = (bid - NB)*64 + w*16;
    int arow = rowbase + c; if (arow > NN-1) arow = NN-1;
    f32x4 acc[9] = {};
    const bf16x8* sBf = (const bf16x8*)sB;
    #pragma unroll
    for (int ks = 0; ks < 4; ++ks) {
      bf16x8 afrag = *(const bf16x8*)(XB + (size_t)arow*FD + ks*32 + kg*8);
      #pragma unroll
      for (int ct = 0; ct < 9; ++ct)
        acc[ct] = __builtin_amdgcn_mfma_f32_16x16x32_bf16(afrag, sBf[(ct*4+ks)*64 + l], acc[ct], 0, 0, 0);
    }
    float pAL0[4] = {}, pAL1[4] = {};
    #pragma unroll
    for (int ct = 0; ct < 8; ++ct) {
      float bias = bl[ct*16 + c];
      float alv  = al[ct*16 + c];
      #pragma unroll
      for (int r = 0; r < 4; ++r) {
        int row = rowbase + kg*4 + r;
        float xv = acc[ct][r] + bias;
        if (row < NN) XLh[(size_t)row*FD + ct*16 + c] = __float2half(xv);
        if (ct < 4) pAL0[r] = fmaf(xv, alv, pAL0[r]);
        else        pAL1[r] = fmaf(xv, alv, pAL1[r]);
      }
    }
    if (c < 2) {
      float b = brd[c];
      #pragma unroll
      for (int r = 0; r < 4; ++r) {
        int row = rowbase + kg*4 + r;
        if (row < NN) AR[(size_t)row*2 + c] = acc[8][r] + b;
      }
    }
    float m0 = -INFINITY, m1 = -INFINITY;
    #pragma unroll
    for (int r = 0; r < 4; ++r) {
      float v0 = pAL0[r], v1 = pAL1[r];
      #pragma unroll
      for (int off = 1; off < 16; off <<= 1) { v0 += __shfl_xor(v0, off); v1 += __shfl_xor(v1, off); }
      int row = rowbase + kg*4 + r;
      if (c == 0 && row < NN) {
        AL[(size_t)row*2 + 0] = v0;
        AL[(size_t)row*2 + 1] = v1;
        m0 = fmaxf(m0, v0); m1 = fmaxf(m1, v1);
      }
    }
    if (c == 0) { atomicMax(&smaxI[0], fenc(m0)); atomicMax(&smaxI[1], fenc(m1)); }
    __syncthreads();
    if (t < 2) atomicMax(&mAL[t], smaxI[t]);
  }
}

// ---------------- MFMA GEMM (standalone, layer 1) ----------------
__global__ __launch_bounds__(256) void k_gemm_mfma(
    const unsigned short* __restrict__ XB, const unsigned short* __restrict__ Bp,
    const float* __restrict__ bl, const float* __restrict__ al, const float* __restrict__ brd,
    __half* __restrict__ XLh, float* __restrict__ AL, float* __restrict__ AR,
    int* __restrict__ mAL)
{
  __shared__ unsigned short sB[BPSZ];
  __shared__ int smaxI[2];
  int t = threadIdx.x;
  if (t < 2) smaxI[t] = 0x80000000;
  {
    const uint4* s = (const uint4*)Bp;
    uint4* d = (uint4*)sB;
    #pragma unroll
    for (int i = 0; i < 9; ++i) d[t + i*256] = s[t + i*256];
  }
  __syncthreads();
  int w = t >> 6, l = t & 63;
  int c = l & 15, kg = l >> 4;
  int rowbase = blockIdx.x*64 + w*16;
  int arow = rowbase + c; if (arow > NN-1) arow = NN-1;
  f32x4 acc[9] = {};
  const bf16x8* sBf = (const bf16x8*)sB;
  #pragma unroll
  for (int ks = 0; ks < 4; ++ks) {
    bf16x8 afrag = *(const bf16x8*)(XB + (size_t)arow*FD + ks*32 + kg*8);
    #pragma unroll
    for (int ct = 0; ct < 9; ++ct)
      acc[ct] = __builtin_amdgcn_mfma_f32_16x16x32_bf16(afrag, sBf[(ct*4+ks)*64 + l], acc[ct], 0, 0, 0);
  }
  float pAL0[4] = {}, pAL1[4] = {};
  #pragma unroll
  for (int ct = 0; ct < 8; ++ct) {
    float bias = bl[ct*16 + c];
    float alv  = al[ct*16 + c];
    #pragma unroll
    for (int r = 0; r < 4; ++r) {
      int row = rowbase + kg*4 + r;
      float xv = acc[ct][r] + bias;
      if (row < NN) XLh[(size_t)row*FD + ct*16 + c] = __float2half(xv);
      if (ct < 4) pAL0[r] = fmaf(xv, alv, pAL0[r]);
      else        pAL1[r] = fmaf(xv, alv, pAL1[r]);
    }
  }
  if (c < 2) {
    float b = brd[c];
    #pragma unroll
    for (int r = 0; r < 4; ++r) {
      int row = rowbase + kg*4 + r;
      if (row < NN) AR[(size_t)row*2 + c] = acc[8][r] + b;
    }
  }
  float m0 = -INFINITY, m1 = -INFINITY;
  #pragma unroll
  for (int r = 0; r < 4; ++r) {
    float v0 = pAL0[r], v1 = pAL1[r];
    #pragma unroll
    for (int off = 1; off < 16; off <<= 1) { v0 += __shfl_xor(v0, off); v1 += __shfl_xor(v1, off); }
    int row = rowbase + kg*4 + r;
    if (c == 0 && row < NN) {
      AL[(size_t)row*2 + 0] = v0;
      AL[(size_t)row*2 + 1] = v1;
      m0 = fmaxf(m0, v0); m1 = fmaxf(m1, v1);
    }
  }
  if (c == 0) { atomicMax(&smaxI[0], fenc(m0)); atomicMax(&smaxI[1], fenc(m1)); }
  __syncthreads();
  if (t < 2) atomicMax(&mAL[t], smaxI[t]);
}

// ---------------- fused attention + aggregation (bf16 out, both layers) ----------------
__global__ __launch_bounds__(256) void k_agg(
    const __half* __restrict__ XLh, const float* __restrict__ AL,
    const float* __restrict__ AR, const int* __restrict__ mAL,
    const int* __restrict__ row_off, const unsigned short* __restrict__ csr16,
    unsigned short* __restrict__ OUTb)
{
  int node = blockIdx.x * 4 + (threadIdx.x >> 6);
  if (node >= NN) return;
  int lane = threadIdx.x & 63;
  int g = lane >> 4, l = lane & 15;
  bool h1 = (l & 8) != 0;
  float2 ar = ((const float2*)AR)[node];
  float m0 = lrelu(fdec(mAL[0]) + ar.x);
  float m1 = lrelu(fdec(mAL[1]) + ar.y);
  float ar_s = h1 ? ar.y : ar.x;
  float m_s  = h1 ? m1 : m0;
  int ro = node + (node >> 8);
  int beg = row_off[ro], end = row_off[ro + 1];
  float facc[8] = {};
  __half2 hacc[4];
  #pragma unroll
  for (int q = 0; q < 4; ++q) hacc[q] = __half2half2(__float2half(0.f));
  float s_acc = 0.f;
  int flushcnt = 0;
  if (beg < end) {
    int em1 = end - 1;
    int s0 = csr16[min(beg + g,      em1)];
    int s1 = csr16[min(beg + 4 + g,  em1)];
    int s2 = csr16[min(beg + 8 + g,  em1)];
    int s3 = csr16[min(beg + 12 + g, em1)];
    for (int i = beg; i < end; i += 16) {
      int c0 = s0, c1 = s1, c2 = s2, c3 = s3;
      bool v0 = (i + g) < end, v1 = (i + 4 + g) < end,
           v2 = (i + 8 + g) < end, v3 = (i + 12 + g) < end;
      int ni = i + 16;
      if (ni < end) {
        s0 = csr16[min(ni + g,      em1)];
        s1 = csr16[min(ni + 4 + g,  em1)];
        s2 = csr16[min(ni + 8 + g,  em1)];
        s3 = csr16[min(ni + 12 + g, em1)];
      }
      uint4 d0 = *(const uint4*)(XLh + (size_t)c0*FD + 8*l);
      uint4 d1 = *(const uint4*)(XLh + (size_t)c1*FD + 8*l);
      uint4 d2 = *(const uint4*)(XLh + (size_t)c2*FD + 8*l);
      uint4 d3 = *(const uint4*)(XLh + (size_t)c3*FD + 8*l);
      float2 a0 = ((const float2*)AL)[c0];
      float2 a1 = ((const float2*)AL)[c1];
      float2 a2 = ((const float2*)AL)[c2];
      float2 a3 = ((const float2*)AL)[c3];
      float w0 = __expf(lrelu((h1 ? a0.y : a0.x) + ar_s) - m_s);
      float w1 = __expf(lrelu((h1 ? a1.y : a1.x) + ar_s) - m_s);
      float w2 = __expf(lrelu((h1 ? a2.y : a2.x) + ar_s) - m_s);
      float w3 = __expf(lrelu((h1 ? a3.y : a3.x) + ar_s) - m_s);
      w0 = v0 ? w0 : 0.f; w1 = v1 ? w1 : 0.f;
      w2 = v2 ? w2 : 0.f; w3 = v3 ? w3 : 0.f;
      s_acc += (w0 + w1) + (w2 + w3);
      __half2 h0 = __half2half2(__float2half(w0));
      __half2 h1w = __half2half2(__float2half(w1));
      __half2 h2 = __half2half2(__float2half(w2));
      __half2 h3 = __half2half2(__float2half(w3));
      const __half2* f0 = (const __half2*)&d0;
      const __half2* f1 = (const __half2*)&d1;
      const __half2* f2 = (const __half2*)&d2;
      const __half2* f3 = (const __half2*)&d3;
      #pragma unroll
      for (int q = 0; q < 4; ++q) {
        hacc[q] = __hfma2(h0,  f0[q], hacc[q]);
        hacc[q] = __hfma2(h1w, f1[q], hacc[q]);
        hacc[q] = __hfma2(h2,  f2[q], hacc[q]);
        hacc[q] = __hfma2(h3,  f3[q], hacc[q]);
      }
      if (++flushcnt == 8) {
        flushcnt = 0;
        #pragma unroll
        for (int q = 0; q < 4; ++q) {
          float2 f = __half22float2(hacc[q]);
          facc[2*q] += f.x; facc[2*q+1] += f.y;
          hacc[q] = __half2half2(__float2half(0.f));
        }
      }
    }
    #pragma unroll
    for (int q = 0; q < 4; ++q) {
      float2 f = __half22float2(hacc[q]);
      facc[2*q] += f.x; facc[2*q+1] += f.y;
    }
  }
  #pragma unroll
  for (int off = 16; off < 64; off <<= 1) {
    s_acc += __shfl_xor(s_acc, off);
    #pragma unroll
    for (int q = 0; q < 8; ++q) facc[q] += __shfl_xor(facc[q], off);
  }
  if (g == 0) {
    float sinv = 1.f / (s_acc + 1e-16f);
    unsigned short ob[8];
    #pragma unroll
    for (int q = 0; q < 8; ++q) ob[q] = f2bf(fmaxf(facc[q]*sinv, 0.f));
    *(uint4*)&OUTb[(size_t)node*FD + 8*l] = *(uint4*)ob;
  }
}

// ---------------- post_mp (collapsed) + log_softmax, tiled GEMM (bf16 input) ----------------
__global__ __launch_bounds__(256) void k_post(
    const unsigned short* __restrict__ H, const float* __restrict__ Wp, const float* __restrict__ bp,
    float* __restrict__ out)
{
  __shared__ float sW[FD*OUTD];
  __shared__ float sB[OUTD];
  __shared__ float sX[64][FD+1];
  int t = threadIdx.x;
  for (int i = t; i < FD*OUTD; i += 256) sW[i] = Wp[i];
  if (t < OUTD) sB[t] = bp[t];
  int base = blockIdx.x * 64;
  int rows = NN - base; if (rows > 64) rows = 64;
  const uint4* H8 = (const uint4*)(H + (size_t)base * FD);
  int nf8 = rows * (FD/8);
  for (int i = t; i < nf8; i += 256) {
    uint4 v = H8[i];
    int n = i >> 4, c = (i & 15) * 8;
    const unsigned short* pv = (const unsigned short*)&v;
    #pragma unroll
    for (int q = 0; q < 8; ++q) sX[n][c + q] = bf2f(pv[q]);
  }
  __syncthreads();
  int n = t >> 2, cg = t & 3;
  int node = base + n;
  float acc[10];
  #pragma unroll
  for (int j = 0; j < 10; ++j) acc[j] = sB[cg*10 + j];
  #pragma unroll 4
  for (int k = 0; k < FD; ++k) {
    float xv = sX[n][k];
    const float* wrow = &sW[k*OUTD + cg*10];
    #pragma unroll
    for (int j = 0; j < 10; ++j) acc[j] = fmaf(xv, wrow[j], acc[j]);
  }
  float m = acc[0];
  #pragma unroll
  for (int j = 1; j < 10; ++j) m = fmaxf(m, acc[j]);
  m = fmaxf(m, __shfl_xor(m, 1));
  m = fmaxf(m, __shfl_xor(m, 2));
  float s = 0.f;
  #pragma unroll
  for (int j = 0; j < 10; ++j) s += __expf(acc[j] - m);
  s += __shfl_xor(s, 1);
  s += __shfl_xor(s, 2);
  float lg = m + __logf(s);
  if (node < NN) {
    #pragma unroll
    for (int j = 0; j < 10; ++j) out[(size_t)node*OUTD + cg*10 + j] = acc[j] - lg;
  }
}

// ---------------- launch ----------------
extern "C" void kernel_launch(void* const* d_in, const int* in_sizes, int n_in,
                              void* d_out, int out_size, void* d_ws, size_t ws_size,
                              hipStream_t stream)
{
  const float* x   = (const float*)d_in[0];
  const int*   ei  = (const int*)d_in[1];
  const float* Wl0 = (const float*)d_in[2];
  const float* bl0 = (const float*)d_in[3];
  const float* Wr0 = (const float*)d_in[4];
  const float* br0 = (const float*)d_in[5];
  const float* al0 = (const float*)d_in[6];
  const float* ar0 = (const float*)d_in[7];
  const float* Wl1 = (const float*)d_in[8];
  const float* bl1 = (const float*)d_in[9];
  const float* Wr1 = (const float*)d_in[10];
  const float* br1 = (const float*)d_in[11];
  const float* al1 = (const float*)d_in[12];
  const float* ar1 = (const float*)d_in[13];
  const float* Wm1 = (const float*)d_in[14];
  const float* bm1 = (const float*)d_in[15];
  const float* Wm2 = (const float*)d_in[16];
  const float* bm2 = (const float*)d_in[17];
  const int* srcA = ei;
  const int* dstA = ei + EE;

  char* w = (char*)d_ws;
  __half* XLh    = (__half*)w;          w += (size_t)NN*FD*2;   // 12.8 MB
  float* bufB    = (float*)w;           w += (size_t)NN*FD*4;   // 25.6 MB (pslot/cnt overlay only)
  unsigned short* XB = (unsigned short*)w; w += (size_t)NN*FD*2; // 12.8 MB (bf16 features, both layers)
  float* AL      = (float*)w;  w += (size_t)NN*2*4;
  float* AR      = (float*)w;  w += (size_t)NN*2*4;
  float* brd0    = (float*)w;  w += 16;
  float* brd1    = (float*)w;  w += 16;
  float* Wp      = (float*)w;  w += FD*OUTD*4;
  float* bp      = (float*)w;  w += 64*4;
  int* mAL       = (int*)w;    w += 4*4;
  int* row_off   = (int*)w;    w += (size_t)(NB*257 + 1)*4 + 12;
  unsigned short* csr16 = (unsigned short*)w; w += (size_t)NB*BMAX*2; // 3.6 MB
  unsigned short* Bp0   = (unsigned short*)w; w += BPSZ*2;
  unsigned short* Bp1   = (unsigned short*)w; w += BPSZ*2;
  unsigned int* pslot = (unsigned int*)bufB;                       // 16.05 MB overlay
  int* cnt = (int*)((char*)bufB + (size_t)ABLK*NB*SLOTB*4);        // 200 KB overlay

  // 1) setup + CSR pass A (merged, role-split)
  k_setup<<<SETUP_BLOCKS, 256, 0, stream>>>(x, srcA, dstA,
                                            Wl0, Wr0, ar0, br0, Wl1, Wr1, ar1, br1,
                                            Wm1, bm1, Wm2, bm2, XB, Bp0, Bp1,
                                            brd0, brd1, Wp, bp, mAL, cnt, pslot);

  // 2) CSR finalize + layer-0 gemm (merged, role-split)
  k_bfgemm<<<NB + (NN+63)/64, 256, 0, stream>>>(pslot, cnt, row_off, csr16,
                                                XB, Bp0, bl0, al0, brd0, XLh, AL, AR, mAL + 0);
  // 3) layer-0 agg -> bf16 features into XB (dead after this point until gemm1)
  k_agg<<<(NN+3)/4, 256, 0, stream>>>(XLh, AL, AR, mAL + 0, row_off, csr16, XB);
  // 4) layer-1 gemm (consumes XB, writes XLh/AL/AR)
  k_gemm_mfma<<<(NN+63)/64, 256, 0, stream>>>(XB, Bp1, bl1, al1, brd1, XLh, AL, AR, mAL + 2);
  // 5) layer-1 agg -> bf16 H into XB (XB dead again after gemm1)
  k_agg<<<(NN+3)/4, 256, 0, stream>>>(XLh, AL, AR, mAL + 2, row_off, csr16, XB);
  // 6) post_mp + log_softmax (bf16 input)
  k_post<<<(NN+63)/64, 256, 0, stream>>>(XB, Wp, bp, (float*)d_out);
}